// Round 5
// baseline (94.615 us; speedup 1.0000x reference)
//
#include <hip/hip_runtime.h>
#include <stdint.h>

typedef int i32x4 __attribute__((ext_vector_type(4)));
typedef float f32x4 __attribute__((ext_vector_type(4)));

#define N_IMG 32
#define C_IN 256
#define H_IN 56
#define W_IN 56
#define K_OUT 256
#define H_OUT 54
#define W_OUT 54
#define HW_OUT 2916          // 54*54
#define M_PIX 93312          // 32*2916 = 192 * 486
#define CHW_OUT 746496       // 256*2916

#define BM 192               // pixel rows per block (M_PIX/BM = 486 exact)

#define XT_BYTES ((size_t)N_IMG * H_IN * W_IN * C_IN)   // 25,690,112 (i8 NHWC)
#define WT_BYTES ((size_t)9 * K_OUT * C_IN)             // 589,824   (i8 [rs][k][c])

// LDS: halo @0 (448 rows x 128B = 57344), B dbuf @57344 (2 x 32768) -> 122880
#define HALO_ROWS 448
#define B_OFF 57344
#define B_STRIDE 32768

// -------- fused transforms: x NCHW i32 -> NHWC i8 ; w OIHW f32 -> [rs][k][c] i8 ----
__global__ __launch_bounds__(256) void xform(const int* __restrict__ x,
                                             const float* __restrict__ w,
                                             unsigned char* __restrict__ xt,
                                             unsigned char* __restrict__ wt) {
    const int bid = blockIdx.x;
    if (bid < N_IMG * H_IN) {
        const int n = bid / H_IN;
        const int h = bid % H_IN;
        const int c = threadIdx.x;
        const int* src = x + ((size_t)((n * C_IN + c) * H_IN + h)) * W_IN;
        unsigned char* dst = xt + ((size_t)(n * H_IN + h) * W_IN) * C_IN + c;
        #pragma unroll
        for (int w0 = 0; w0 < W_IN; w0 += 4) {
            int4 v = *(const int4*)(src + w0);
            int a[4] = {v.x, v.y, v.z, v.w};
            #pragma unroll
            for (int j = 0; j < 4; ++j) {
                int q = a[j] < 0 ? 0 : (a[j] > 7 ? 7 : a[j]);
                dst[(size_t)(w0 + j) * C_IN] = (unsigned char)q;
            }
        }
    } else {
        const int k = bid - N_IMG * H_IN;
        const int c = threadIdx.x;
        const float* src = w + ((size_t)k * C_IN + c) * 9;
        #pragma unroll
        for (int rs = 0; rs < 9; ++rs) {
            int iv = (int)src[rs];   // truncation == astype(int32); values 0..6
            wt[((size_t)rs * K_OUT + k) * C_IN + c] = (unsigned char)iv;
        }
    }
}

// -------- async global->LDS (width 16) --------
__device__ __forceinline__ void gload_lds16(const void* g, void* l) {
    __builtin_amdgcn_global_load_lds(
        (const __attribute__((address_space(1))) uint32_t*)g,
        (__attribute__((address_space(3))) uint32_t*)l,
        16, 0, 0);
}

__device__ __forceinline__ unsigned lds_off(const void* p) {
    return (unsigned)(unsigned long long)(__attribute__((address_space(3))) const char*)p;
}

#define DSREAD(dst, addr) \
    asm volatile("ds_read_b128 %0, %1" : "=v"(dst) : "v"(addr))

// -------- main conv (i8): BM=192 pix, BN=256 ch; halo-A + B double-buffer --------
__global__ __launch_bounds__(512) void conv_mfma(const unsigned char* __restrict__ xt,
                                                 const unsigned char* __restrict__ wt,
                                                 float* __restrict__ out) {
    __shared__ __align__(16) unsigned char lds[122880];

    const int t512 = threadIdx.x;
    const int l    = t512 & 63;
    const int wid  = t512 >> 6;
    const int wr   = wid >> 2;     // 0..1 -> 96-pixel half
    const int wc   = wid & 3;      // 0..3 -> 64-channel quarter
    const int mb   = blockIdx.x;   // 486 M-tiles

    // staging thread geometry (both-sides swizzle, proven R4 pattern)
    const int srow = t512 >> 3;
    const int cs   = (((t512 & 7) ^ (srow & 7)) << 4);
    const int tb16 = t512 * 16;

    // block-base input pixel
    const int m0  = mb * BM;
    const int n0  = m0 / HW_OUT;
    const int rm0 = m0 - n0 * HW_OUT;
    const int oh0 = rm0 / W_OUT;
    const int ow0 = rm0 - oh0 * W_OUT;
    const int pix0 = n0 * (H_IN * W_IN) + oh0 * W_IN + ow0;

    // per-lane halo row deltas for the 6 M-fragments (exact n/oh/ow mapping)
    const int lrow = l & 15;
    int drow[6];
    #pragma unroll
    for (int mf = 0; mf < 6; ++mf) {
        const int m   = m0 + wr * 96 + mf * 16 + lrow;
        const int n   = m / HW_OUT;
        const int rem = m - n * HW_OUT;
        const int oh  = rem / W_OUT;
        const int ow  = rem - oh * W_OUT;
        drow[mf] = n * (H_IN * W_IN) + oh * W_IN + ow - pix0;   // 0..317
    }

    const int lk = (l >> 4) << 4;                     // 0/16/32/48
    const unsigned swzB = (unsigned)((lrow & 7) << 4);
    unsigned brow128[4];
    #pragma unroll
    for (int nf = 0; nf < 4; ++nf) brow128[nf] = (unsigned)((wc * 64 + nf * 16 + lrow) << 7);
    const unsigned colkB[2] = { ((unsigned)lk) ^ swzB, ((unsigned)(64 + lk)) ^ swzB };

    int bbase[4];
    #pragma unroll
    for (int j = 0; j < 4; ++j) bbase[j] = ((j * 64 + srow) << 8) + cs;  // *256/k-row

    i32x4 acc[6][4];
    #pragma unroll
    for (int i = 0; i < 6; ++i)
        #pragma unroll
        for (int j = 0; j < 4; ++j)
            acc[i][j] = (i32x4){0, 0, 0, 0};

    const char* xb = (const char*)xt;
    const char* wb = (const char*)wt;
    const unsigned ldsb = lds_off(lds);

    #define STAGE_HALO(CH) do {                                             \
        const char* hsrc_ = xb + (size_t)pix0 * 256 + (size_t)(CH) * 128;   \
        _Pragma("unroll")                                                   \
        for (int i_ = 0; i_ < 7; ++i_)                                      \
            gload_lds16(hsrc_ + (size_t)(((i_ * 64 + srow) << 8) + cs),     \
                        lds + i_ * 8192 + tb16);                            \
    } while (0)

    #define STAGE_B(TAP, CH, SEL) do {                                      \
        const char* bsrc_ = wb + (size_t)(TAP) * (K_OUT * C_IN) + (size_t)(CH) * 128; \
        unsigned char* bdst_ = lds + B_OFF + (size_t)(SEL) * B_STRIDE + tb16; \
        gload_lds16(bsrc_ + bbase[0], bdst_);                               \
        gload_lds16(bsrc_ + bbase[1], bdst_ + 8192);                        \
        gload_lds16(bsrc_ + bbase[2], bdst_ + 16384);                       \
        gload_lds16(bsrc_ + bbase[3], bdst_ + 24576);                       \
    } while (0)

    // one K-step g (=ch*9+tap): two 24-MFMA phases; prefetch B(g+1) in phase 1
    #define KBODY(G, DO_STAGE) do {                                         \
        const int ch_  = ((G) >= 9) ? 1 : 0;                                \
        const int tap_ = (G) - ch_ * 9;                                     \
        const int r_   = (tap_ * 11) >> 5;                                  \
        const int s_   = tap_ - r_ * 3;                                     \
        const int toff_ = r_ * W_IN + s_;                                   \
        const unsigned bB_ = ldsb + B_OFF + ((unsigned)((G) & 1)) * B_STRIDE; \
        i32x4 a0[6], b0[4], a1[6], b1[4];                                   \
        unsigned abase_[6], aswz_[6];                                       \
        _Pragma("unroll")                                                   \
        for (int mf = 0; mf < 6; ++mf) {                                    \
            const int row_ = drow[mf] + toff_;                              \
            abase_[mf] = ldsb + ((unsigned)row_ << 7);                      \
            aswz_[mf]  = ((unsigned)(row_ & 7)) << 4;                       \
            DSREAD(a0[mf], abase_[mf] + (((unsigned)lk) ^ aswz_[mf]));      \
        }                                                                   \
        _Pragma("unroll")                                                   \
        for (int nf = 0; nf < 4; ++nf) DSREAD(b0[nf], bB_ + brow128[nf] + colkB[0]); \
        if (DO_STAGE) {                                                     \
            const int g1_ = (G) + 1;                                        \
            const int c1_ = (g1_ >= 9) ? 1 : 0;                             \
            STAGE_B(g1_ - c1_ * 9, c1_, (g1_ & 1));                         \
        }                                                                   \
        _Pragma("unroll")                                                   \
        for (int mf = 0; mf < 6; ++mf)                                      \
            DSREAD(a1[mf], abase_[mf] + (((unsigned)(64 + lk)) ^ aswz_[mf])); \
        _Pragma("unroll")                                                   \
        for (int nf = 0; nf < 4; ++nf) DSREAD(b1[nf], bB_ + brow128[nf] + colkB[1]); \
        asm volatile("s_waitcnt lgkmcnt(10)" ::: "memory");                 \
        __builtin_amdgcn_sched_barrier(0);                                  \
        __builtin_amdgcn_s_setprio(1);                                      \
        _Pragma("unroll")                                                   \
        for (int mf = 0; mf < 6; ++mf)                                      \
            _Pragma("unroll")                                               \
            for (int nf = 0; nf < 4; ++nf)                                  \
                acc[mf][nf] = __builtin_amdgcn_mfma_i32_16x16x64_i8(        \
                    a0[mf], b0[nf], acc[mf][nf], 0, 0, 0);                  \
        __builtin_amdgcn_s_setprio(0);                                      \
        asm volatile("s_waitcnt lgkmcnt(0)" ::: "memory");                  \
        __builtin_amdgcn_sched_barrier(0);                                  \
        __builtin_amdgcn_s_setprio(1);                                      \
        _Pragma("unroll")                                                   \
        for (int mf = 0; mf < 6; ++mf)                                      \
            _Pragma("unroll")                                               \
            for (int nf = 0; nf < 4; ++nf)                                  \
                acc[mf][nf] = __builtin_amdgcn_mfma_i32_16x16x64_i8(        \
                    a1[mf], b1[nf], acc[mf][nf], 0, 0, 0);                  \
        __builtin_amdgcn_s_setprio(0);                                      \
    } while (0)

    // ---- prologue: halo(ch0) + B(step 0) ----
    STAGE_HALO(0);
    STAGE_B(0, 0, 0);
    asm volatile("s_waitcnt vmcnt(0)" ::: "memory");
    __builtin_amdgcn_s_barrier();

    // ---- 18 K-steps; halo restage for ch1 between g=8 and g=9 ----
    for (int g = 0; g < 18; ++g) {
        KBODY(g, (g < 17));
        if (g < 17) {
            asm volatile("s_waitcnt vmcnt(0)" ::: "memory");
            __builtin_amdgcn_s_barrier();
        }
        if (g == 8) {
            STAGE_HALO(1);
            asm volatile("s_waitcnt vmcnt(0)" ::: "memory");
            __builtin_amdgcn_s_barrier();
        }
    }

    // ---- epilogue: C/D col=lane&15, row=(lane>>4)*4+reg; float4 stores ----
    const int c16 = l & 15;
    const int p4  = (l >> 4) << 2;
    #pragma unroll
    for (int mf = 0; mf < 6; ++mf) {
        const int m   = mb * BM + wr * 96 + mf * 16 + p4;
        const int n   = m / HW_OUT;
        const int rem = m - n * HW_OUT;
        float* ob = out + (size_t)n * CHW_OUT + rem;
        #pragma unroll
        for (int nf = 0; nf < 4; ++nf) {
            const int ch = wc * 64 + nf * 16 + c16;
            f32x4 v;
            #pragma unroll
            for (int j = 0; j < 4; ++j) v[j] = (float)acc[mf][nf][j];
            *(f32x4*)(ob + (size_t)ch * HW_OUT) = v;
        }
    }
    #undef KBODY
    #undef STAGE_B
    #undef STAGE_HALO
}

// -------- fallback (only if ws too small): naive direct conv, exact --------
__global__ __launch_bounds__(256) void conv_naive(const int* __restrict__ x,
                                                  const float* __restrict__ w,
                                                  float* __restrict__ out) {
    int idx = blockIdx.x * 256 + threadIdx.x;
    if (idx >= N_IMG * K_OUT * HW_OUT) return;
    const int wo = idx % W_OUT;
    int tmp = idx / W_OUT;
    const int ho = tmp % H_OUT; tmp /= H_OUT;
    const int k = tmp % K_OUT;
    const int n = tmp / K_OUT;
    float acc = 0.f;
    for (int c = 0; c < C_IN; ++c) {
        const int* xp = x + ((size_t)((n * C_IN + c) * H_IN + ho)) * W_IN + wo;
        const float* wp = w + ((size_t)(k * C_IN + c)) * 9;
        #pragma unroll
        for (int r = 0; r < 3; ++r)
            #pragma unroll
            for (int s = 0; s < 3; ++s) {
                int xv = xp[r * W_IN + s];
                xv = xv < 0 ? 0 : (xv > 7 ? 7 : xv);
                acc += (float)xv * (float)(int)wp[r * 3 + s];
            }
    }
    out[idx] = acc;
}

extern "C" void kernel_launch(void* const* d_in, const int* in_sizes, int n_in,
                              void* d_out, int out_size, void* d_ws, size_t ws_size,
                              hipStream_t stream) {
    const int*   x = (const int*)d_in[0];
    const float* w = (const float*)d_in[1];
    float* out = (float*)d_out;

    const size_t need = XT_BYTES + WT_BYTES;   // ~26.3 MB
    if (ws_size >= need) {
        unsigned char* xt = (unsigned char*)d_ws;
        unsigned char* wt = (unsigned char*)((char*)d_ws + XT_BYTES);
        hipLaunchKernelGGL(xform, dim3(N_IMG * H_IN + K_OUT), dim3(256), 0, stream,
                           x, w, xt, wt);
        hipLaunchKernelGGL(conv_mfma, dim3(M_PIX / BM), dim3(512), 0, stream,
                           xt, wt, out);
    } else {
        const int total = N_IMG * K_OUT * HW_OUT;
        hipLaunchKernelGGL(conv_naive, dim3((total + 255) / 256), dim3(256), 0, stream, x, w, out);
    }
}